// Round 8
// baseline (932.164 us; speedup 1.0000x reference)
//
#include <hip/hip_runtime.h>

#define H    128
#define NMQ  50000
#define NSQ  50000
#define NE   600000
#define NEL  200000
#define FIN  768
#define NLAYERS 4
#define GCHUNK 64

typedef __attribute__((ext_vector_type(8))) short bf16x8;
typedef __attribute__((ext_vector_type(4))) float f32x4;

__device__ inline ushort f2b(float f) {
  unsigned u = __float_as_uint(f);
  u = (u + 0x7FFFu + ((u >> 16) & 1u)) >> 16;
  return (ushort)u;
}
__device__ inline float b2f(ushort h) { return __uint_as_float((unsigned)h << 16); }

#define GLOAD_LDS(gp, lp) \
  __builtin_amdgcn_global_load_lds((const __attribute__((address_space(1))) void*)(gp), \
                                   (__attribute__((address_space(3))) void*)(lp), 4, 0, 0)

// ---------------- generic fp32 -> bf16 convert (n divisible by 4) ----------------
__global__ void cvt_bf16(const float* __restrict__ in, ushort* __restrict__ out, int n4) {
  int i = blockIdx.x * blockDim.x + threadIdx.x;
  if (i >= n4) return;
  float4 v = ((const float4*)in)[i];
  ushort4 o;
  o.x = f2b(v.x); o.y = f2b(v.y); o.z = f2b(v.z); o.w = f2b(v.w);
  ((ushort4*)out)[i] = o;
}

// ---------------- encoder: x_sq = bf16(sq_x @ lin_W^T + lin_b + movie_emb) ----------------
// One wave per 16 rows (grid 3125). No LDS, no barriers. (r6 known-good form)
__global__ __launch_bounds__(64) void encoder_mfma(
    const float* __restrict__ A, const ushort* __restrict__ Wb,
    const float* __restrict__ bias, const float* __restrict__ memb,
    ushort* __restrict__ C)
{
  int lane = threadIdx.x;
  int rowbase = blockIdx.x * 16;
  int t = lane >> 4, fr = lane & 15;
  f32x4 acc[8];
  #pragma unroll
  for (int c = 0; c < 8; ++c)
    #pragma unroll
    for (int q = 0; q < 4; ++q) acc[c][q] = 0.f;

  int arow = rowbase + fr;
  const float* Abase = A + (long)arow * FIN + t * 8;

  for (int k0 = 0; k0 < FIN; k0 += 32) {
    bf16x8 af, bfm[8];
    {
      const float* p = Abase + k0;
      float4 v0 = *(const float4*)p;
      float4 v1 = *(const float4*)(p + 4);
      ushort tmp[8];
      tmp[0] = f2b(v0.x); tmp[1] = f2b(v0.y); tmp[2] = f2b(v0.z); tmp[3] = f2b(v0.w);
      tmp[4] = f2b(v1.x); tmp[5] = f2b(v1.y); tmp[6] = f2b(v1.z); tmp[7] = f2b(v1.w);
      af = *(bf16x8*)tmp;
    }
    #pragma unroll
    for (int cc = 0; cc < 8; ++cc) {
      int col = cc * 16 + fr;
      bfm[cc] = *(const bf16x8*)(Wb + (long)col * FIN + k0 + t * 8);
    }
    #pragma unroll
    for (int cc = 0; cc < 8; ++cc)
      acc[cc] = __builtin_amdgcn_mfma_f32_16x16x32_bf16(af, bfm[cc], acc[cc], 0, 0, 0);
  }
  #pragma unroll
  for (int cc = 0; cc < 8; ++cc)
    #pragma unroll
    for (int q = 0; q < 4; ++q) {
      int row = rowbase + t * 4 + q;
      int col = cc * 16 + fr;
      float v = acc[cc][q] + bias[col] + memb[(long)row * H + col];
      C[(long)row * H + col] = f2b(v);
    }
}

// ---------------- fused SpMM-mean + SAGE GEMM ----------------
// One wave per 16 dst rows. Gather phase: edges staged 64-deep into LDS via
// global_load_lds (zero VGPR cost -> 128 cache lines in flight per burst),
// consumed with a CSR-run-length flush into the swizzled mean tile.
__global__ __launch_bounds__(64) void fused_layer(
    const ushort* __restrict__ xg,    // gather source (other node type) bf16
    const ushort* __restrict__ xs,    // self features [M, H] bf16
    const int* __restrict__ offs, const int* __restrict__ csr,
    const int* __restrict__ drow,     // dst row per CSR slot
    const ushort* __restrict__ Wl, const ushort* __restrict__ Wr,
    const float* __restrict__ bias,
    ushort* __restrict__ Cout, int M, int relu)
{
  __shared__ unsigned stage[GCHUNK * 64];  // 16 KB: 64 staged rows x 256 B
  __shared__ ushort mtile[16 * 128];       // 4 KB swizzled means
  int lane = threadIdx.x;
  int rowbase = blockIdx.x * 16;           // M % 16 == 0
  unsigned* mt32 = (unsigned*)mtile;
  int wslot = lane >> 2;

  #pragma unroll
  for (int i = 0; i < 16; ++i) mt32[i * 64 + lane] = 0;

  int cbeg = offs[rowbase], cend = offs[rowbase + 16];
  float a0 = 0.f, a1 = 0.f;
  int cur = -1, cnt = 0;

  for (int c = cbeg; c < cend; c += GCHUNK) {
    int n = cend - c; if (n > GCHUNK) n = GCHUNK;
    // ---- issue: stage n rows into LDS (no VGPR destinations) ----
    if (n == GCHUNK) {
      #pragma unroll
      for (int j = 0; j < GCHUNK; ++j) {
        long r = csr[c + j];
        GLOAD_LDS((const char*)xg + r * 256 + lane * 4, &stage[j * 64]);
      }
    } else {
      for (int j = 0; j < n; ++j) {
        long r = csr[c + j];
        GLOAD_LDS((const char*)xg + r * 256 + lane * 4, &stage[j * 64]);
      }
    }
    asm volatile("s_waitcnt vmcnt(0)" ::: "memory");
    __builtin_amdgcn_sched_barrier(0);
    // ---- consume: run-length accumulate, flush on row change ----
    for (int j = 0; j < n; ++j) {
      int rowj = drow[c + j];
      if (rowj != cur) {
        if (cnt > 0) {
          float inv = 1.f / (float)cnt;
          int sw = (wslot & 8) | ((wslot & 7) ^ (cur & 7));
          mt32[(cur & 15) * 64 + sw * 4 + (lane & 3)] =
              (unsigned)f2b(a0 * inv) | ((unsigned)f2b(a1 * inv) << 16);
        }
        cur = rowj; a0 = 0.f; a1 = 0.f; cnt = 0;
      }
      unsigned w = stage[j * 64 + lane];
      a0 += b2f((ushort)(w & 0xffff));
      a1 += b2f((ushort)(w >> 16));
      ++cnt;
    }
  }
  if (cnt > 0) {
    float inv = 1.f / (float)cnt;
    int sw = (wslot & 8) | ((wslot & 7) ^ (cur & 7));
    mt32[(cur & 15) * 64 + sw * 4 + (lane & 3)] =
        (unsigned)f2b(a0 * inv) | ((unsigned)f2b(a1 * inv) << 16);
  }
  // wave-local LDS: no barrier needed (one wave per block)

  // ---- GEMM phase: out = mean @ Wl^T + bl + self @ Wr^T ----
  int t = lane >> 4, fr = lane & 15;
  f32x4 acc[8];
  #pragma unroll
  for (int c = 0; c < 8; ++c)
    #pragma unroll
    for (int q = 0; q < 4; ++q) acc[c][q] = 0.f;

  // mean side (A from LDS), K = 128
  #pragma unroll
  for (int ks = 0; ks < 4; ++ks) {
    int slot = ks * 4 + t;
    int sw = (slot & 8) | ((slot & 7) ^ (fr & 7));
    bf16x8 af = *(const bf16x8*)&mtile[fr * 128 + sw * 8];
    bf16x8 bfm[8];
    #pragma unroll
    for (int cc = 0; cc < 8; ++cc) {
      int col = cc * 16 + fr;
      bfm[cc] = *(const bf16x8*)(Wl + (long)col * H + slot * 8);
    }
    #pragma unroll
    for (int cc = 0; cc < 8; ++cc)
      acc[cc] = __builtin_amdgcn_mfma_f32_16x16x32_bf16(af, bfm[cc], acc[cc], 0, 0, 0);
  }
  // self side (A direct from global), K = 128
  int srow = rowbase + fr;
  #pragma unroll
  for (int ks = 0; ks < 4; ++ks) {
    int slot = ks * 4 + t;
    bf16x8 af = *(const bf16x8*)(xs + (long)srow * H + slot * 8);
    bf16x8 bfm[8];
    #pragma unroll
    for (int cc = 0; cc < 8; ++cc) {
      int col = cc * 16 + fr;
      bfm[cc] = *(const bf16x8*)(Wr + (long)col * H + slot * 8);
    }
    #pragma unroll
    for (int cc = 0; cc < 8; ++cc)
      acc[cc] = __builtin_amdgcn_mfma_f32_16x16x32_bf16(af, bfm[cc], acc[cc], 0, 0, 0);
  }
  // epilogue
  #pragma unroll
  for (int cc = 0; cc < 8; ++cc)
    #pragma unroll
    for (int q = 0; q < 4; ++q) {
      int row = rowbase + t * 4 + q;
      int col = cc * 16 + fr;
      float v = acc[cc][q] + bias[col];
      if (relu) v = fmaxf(v, 0.f);
      Cout[(long)row * H + col] = f2b(v);
    }
}

// ---------------- degree count ----------------
__global__ void deg_count(const int* __restrict__ eidx, int* __restrict__ df, int* __restrict__ dr) {
  int e = blockIdx.x * blockDim.x + threadIdx.x;
  if (e >= NE) return;
  atomicAdd(dr + eidx[e], 1);
  atomicAdd(df + eidx[NE + e], 1);
}

// ---------------- dual exclusive scan: block 0 -> forward, block 1 -> reverse ----------------
__global__ __launch_bounds__(1024) void exscan2(
    const int* __restrict__ degf, const int* __restrict__ degr,
    int* __restrict__ offf, int* __restrict__ offr)
{
  __shared__ int part[1024];
  const int* deg = blockIdx.x ? degr : degf;
  int* offs = blockIdx.x ? offr : offf;
  int n = blockIdx.x ? NMQ : NSQ;
  int t = threadIdx.x;
  int chunk = (n + 1023) >> 10;
  int beg = t * chunk, end = beg + chunk;
  if (end > n) end = n;
  int s = 0;
  for (int i = beg; i < end; ++i) s += deg[i];
  part[t] = s;
  __syncthreads();
  for (int offd = 1; offd < 1024; offd <<= 1) {
    int v = 0;
    if (t >= offd) v = part[t - offd];
    __syncthreads();
    part[t] += v;
    __syncthreads();
  }
  int run = (t == 0) ? 0 : part[t - 1];
  for (int i = beg; i < end; ++i) { offs[i] = run; run += deg[i]; }
  if (t == 1023) offs[n] = part[1023];
}

// ---------------- CSR fill (also records dst row per slot) ----------------
__global__ void csr_fill(const int* __restrict__ eidx,
                         const int* __restrict__ offs_f, const int* __restrict__ offs_r,
                         int* __restrict__ cur_f, int* __restrict__ cur_r,
                         int* __restrict__ csr_f, int* __restrict__ csr_r,
                         int* __restrict__ drow_f, int* __restrict__ drow_r) {
  int e = blockIdx.x * blockDim.x + threadIdx.x;
  if (e >= NE) return;
  int s = eidx[e], d = eidx[NE + e];
  int p = atomicAdd(cur_f + d, 1); int pf = offs_f[d] + p; csr_f[pf] = s; drow_f[pf] = d;
  int q = atomicAdd(cur_r + s, 1); int pr = offs_r[s] + q; csr_r[pr] = d; drow_r[pr] = s;
}

// ---------------- classifier: one wave per label edge ----------------
__global__ __launch_bounds__(256) void edge_dot_b(
    const ushort* __restrict__ xmq, const ushort* __restrict__ xsq,
    const int* __restrict__ eli, float* __restrict__ out)
{
  int wid = (blockIdx.x << 2) + (threadIdx.x >> 6);
  int lane = threadIdx.x & 63;
  if (wid >= NEL) return;
  int a = eli[wid], b = eli[NEL + wid];
  unsigned xa = ((const unsigned*)xmq)[(long)a * 64 + lane];
  unsigned xb = ((const unsigned*)xsq)[(long)b * 64 + lane];
  float p = b2f((ushort)(xa & 0xffff)) * b2f((ushort)(xb & 0xffff))
          + b2f((ushort)(xa >> 16))    * b2f((ushort)(xb >> 16));
  #pragma unroll
  for (int off = 32; off; off >>= 1) p += __shfl_down(p, off, 64);
  if (lane == 0) out[wid] = p;
}

extern "C" void kernel_launch(void* const* d_in, const int* in_sizes, int n_in,
                              void* d_out, int out_size, void* d_ws, size_t ws_size,
                              hipStream_t stream) {
  (void)in_sizes; (void)n_in; (void)out_size; (void)ws_size;
  // d_in[0]=mq_node_id (arange, unused), d_in[1]=sq_node_id (arange, unused)
  const float* sq_x      = (const float*)d_in[2];
  const int*   eidx      = (const int*)d_in[3];
  const int*   eli       = (const int*)d_in[4];
  const float* user_emb  = (const float*)d_in[5];
  const float* movie_emb = (const float*)d_in[6];
  const float* lin_W     = (const float*)d_in[7];
  const float* lin_b     = (const float*)d_in[8];
  const float* Wl_s      = (const float*)d_in[9];
  const float* bl_s      = (const float*)d_in[10];
  const float* Wr_s      = (const float*)d_in[11];
  const float* Wl_m      = (const float*)d_in[12];
  const float* bl_m      = (const float*)d_in[13];
  const float* Wr_m      = (const float*)d_in[14];
  float* out = (float*)d_out;

  char* ws = (char*)d_ws;
  size_t off = 0;
  auto alloc = [&](size_t bytes) {
    char* p = ws + off;
    off += (bytes + 255) & ~(size_t)255;
    return p;
  };
  ushort* xmq_a = (ushort*)alloc((size_t)NMQ * H * 2);
  ushort* xmq_b = (ushort*)alloc((size_t)NMQ * H * 2);
  ushort* xsq_a = (ushort*)alloc((size_t)NSQ * H * 2);
  ushort* xsq_b = (ushort*)alloc((size_t)NSQ * H * 2);
  ushort* linWb = (ushort*)alloc((size_t)H * FIN * 2);
  ushort* Wlsb  = (ushort*)alloc((size_t)NLAYERS * H * H * 2);
  ushort* Wrsb  = (ushort*)alloc((size_t)NLAYERS * H * H * 2);
  ushort* Wlmb  = (ushort*)alloc((size_t)NLAYERS * H * H * 2);
  ushort* Wrmb  = (ushort*)alloc((size_t)NLAYERS * H * H * 2);
  int* deg_f  = (int*)alloc((size_t)NSQ * 4);
  int* deg_r  = (int*)alloc((size_t)NMQ * 4);
  int* cur_f  = (int*)alloc((size_t)NSQ * 4);
  int* cur_r  = (int*)alloc((size_t)NMQ * 4);
  int* offs_f = (int*)alloc((size_t)(NSQ + 1) * 4);
  int* offs_r = (int*)alloc((size_t)(NMQ + 1) * 4);
  int* csr_f  = (int*)alloc((size_t)NE * 4);
  int* csr_r  = (int*)alloc((size_t)NE * 4);
  int* drow_f = (int*)alloc((size_t)NE * 4);
  int* drow_r = (int*)alloc((size_t)NE * 4);

  hipMemsetAsync(deg_f, 0, (char*)offs_f - (char*)deg_f, stream);

  // conversions
  cvt_bf16<<<(NMQ * H / 4 + 255) / 256, 256, 0, stream>>>(user_emb, xmq_a, NMQ * H / 4);
  cvt_bf16<<<(H * FIN / 4 + 255) / 256, 256, 0, stream>>>(lin_W, linWb, H * FIN / 4);
  cvt_bf16<<<(NLAYERS * H * H / 4 + 255) / 256, 256, 0, stream>>>(Wl_s, Wlsb, NLAYERS * H * H / 4);
  cvt_bf16<<<(NLAYERS * H * H / 4 + 255) / 256, 256, 0, stream>>>(Wr_s, Wrsb, NLAYERS * H * H / 4);
  cvt_bf16<<<(NLAYERS * H * H / 4 + 255) / 256, 256, 0, stream>>>(Wl_m, Wlmb, NLAYERS * H * H / 4);
  cvt_bf16<<<(NLAYERS * H * H / 4 + 255) / 256, 256, 0, stream>>>(Wr_m, Wrmb, NLAYERS * H * H / 4);

  encoder_mfma<<<NSQ / 16, 64, 0, stream>>>(sq_x, linWb, lin_b, movie_emb, xsq_a);
  deg_count<<<(NE + 255) / 256, 256, 0, stream>>>(eidx, deg_f, deg_r);
  exscan2<<<2, 1024, 0, stream>>>(deg_f, deg_r, offs_f, offs_r);
  csr_fill<<<(NE + 255) / 256, 256, 0, stream>>>(eidx, offs_f, offs_r, cur_f, cur_r,
                                                 csr_f, csr_r, drow_f, drow_r);

  ushort *cm = xmq_a, *cs = xsq_a, *nm = xmq_b, *ns = xsq_b;
  for (int l = 0; l < NLAYERS; ++l) {
    fused_layer<<<NSQ / 16, 64, 0, stream>>>(cm, cs, offs_f, csr_f, drow_f,
        Wlsb + (size_t)l * H * H, Wrsb + (size_t)l * H * H, bl_s + (size_t)l * H,
        ns, NSQ, l == 0);
    fused_layer<<<NMQ / 16, 64, 0, stream>>>(cs, cm, offs_r, csr_r, drow_r,
        Wlmb + (size_t)l * H * H, Wrmb + (size_t)l * H * H, bl_m + (size_t)l * H,
        nm, NMQ, l == 0);
    ushort* t;
    t = cm; cm = nm; nm = t;
    t = cs; cs = ns; ns = t;
  }
  edge_dot_b<<<(NEL + 3) / 4, 256, 0, stream>>>(cm, cs, eli, out);
}

// Round 9
// 724.757 us; speedup vs baseline: 1.2862x; 1.2862x over previous
//
#include <hip/hip_runtime.h>

#define H    128
#define NMQ  50000
#define NSQ  50000
#define NE   600000
#define NEL  200000
#define FIN  768
#define NLAYERS 4
#define NBLK (NSQ / 16)   // blocks per side

typedef __attribute__((ext_vector_type(8))) short bf16x8;
typedef __attribute__((ext_vector_type(4))) float f32x4;

__device__ inline ushort f2b(float f) {
  unsigned u = __float_as_uint(f);
  u = (u + 0x7FFFu + ((u >> 16) & 1u)) >> 16;
  return (ushort)u;
}
__device__ inline float b2f(ushort h) { return __uint_as_float((unsigned)h << 16); }

// ---------------- fp32 -> bf16 convert (n divisible by 4) ----------------
__global__ void cvt_bf16(const float* __restrict__ in, ushort* __restrict__ out, int n4) {
  int i = blockIdx.x * blockDim.x + threadIdx.x;
  if (i >= n4) return;
  float4 v = ((const float4*)in)[i];
  ushort4 o;
  o.x = f2b(v.x); o.y = f2b(v.y); o.z = f2b(v.z); o.w = f2b(v.w);
  ((ushort4*)out)[i] = o;
}

// ---------------- batched weight convert: 5 tensors via blockIdx.y ----------------
__global__ void cvt_w5(const float* __restrict__ linW,
                       const float* __restrict__ Wls, const float* __restrict__ Wrs,
                       const float* __restrict__ Wlm, const float* __restrict__ Wrm,
                       ushort* olinW, ushort* oWls, ushort* oWrs, ushort* oWlm, ushort* oWrm) {
  const float* in; ushort* out; int n4;
  switch (blockIdx.y) {
    case 0: in = linW; out = olinW; n4 = H * FIN / 4; break;
    case 1: in = Wls;  out = oWls;  n4 = NLAYERS * H * H / 4; break;
    case 2: in = Wrs;  out = oWrs;  n4 = NLAYERS * H * H / 4; break;
    case 3: in = Wlm;  out = oWlm;  n4 = NLAYERS * H * H / 4; break;
    default: in = Wrm; out = oWrm;  n4 = NLAYERS * H * H / 4; break;
  }
  int i = blockIdx.x * blockDim.x + threadIdx.x;
  if (i >= n4) return;
  float4 v = ((const float4*)in)[i];
  ushort4 o;
  o.x = f2b(v.x); o.y = f2b(v.y); o.z = f2b(v.z); o.w = f2b(v.w);
  ((ushort4*)out)[i] = o;
}

// ---------------- encoder: x_sq = bf16(sq_x @ lin_W^T + lin_b + movie_emb) ----------------
// One wave per 16 rows (grid 3125). No LDS, no barriers. (r6 known-good form)
__global__ __launch_bounds__(64) void encoder_mfma(
    const float* __restrict__ A, const ushort* __restrict__ Wb,
    const float* __restrict__ bias, const float* __restrict__ memb,
    ushort* __restrict__ C)
{
  int lane = threadIdx.x;
  int rowbase = blockIdx.x * 16;
  int t = lane >> 4, fr = lane & 15;
  f32x4 acc[8];
  #pragma unroll
  for (int c = 0; c < 8; ++c)
    #pragma unroll
    for (int q = 0; q < 4; ++q) acc[c][q] = 0.f;

  int arow = rowbase + fr;
  const float* Abase = A + (long)arow * FIN + t * 8;

  for (int k0 = 0; k0 < FIN; k0 += 32) {
    bf16x8 af, bfm[8];
    {
      const float* p = Abase + k0;
      float4 v0 = *(const float4*)p;
      float4 v1 = *(const float4*)(p + 4);
      ushort tmp[8];
      tmp[0] = f2b(v0.x); tmp[1] = f2b(v0.y); tmp[2] = f2b(v0.z); tmp[3] = f2b(v0.w);
      tmp[4] = f2b(v1.x); tmp[5] = f2b(v1.y); tmp[6] = f2b(v1.z); tmp[7] = f2b(v1.w);
      af = *(bf16x8*)tmp;
    }
    #pragma unroll
    for (int cc = 0; cc < 8; ++cc) {
      int col = cc * 16 + fr;
      bfm[cc] = *(const bf16x8*)(Wb + (long)col * FIN + k0 + t * 8);
    }
    #pragma unroll
    for (int cc = 0; cc < 8; ++cc)
      acc[cc] = __builtin_amdgcn_mfma_f32_16x16x32_bf16(af, bfm[cc], acc[cc], 0, 0, 0);
  }
  #pragma unroll
  for (int cc = 0; cc < 8; ++cc)
    #pragma unroll
    for (int q = 0; q < 4; ++q) {
      int row = rowbase + t * 4 + q;
      int col = cc * 16 + fr;
      float v = acc[cc][q] + bias[col] + memb[(long)row * H + col];
      C[(long)row * H + col] = f2b(v);
    }
}

// ---------------- merged both-sides fused SpMM-mean + SAGE GEMM ----------------
// Grid 2*NBLK. Blocks [0,NBLK): sq side (gather x_mq via csr_f, self x_sq -> nsq).
// Blocks [NBLK,2*NBLK): mq side (gather x_sq via csr_r, self x_mq -> nmq).
// Doubles resident waves per dispatch vs per-side launches (MLP-bound fix).
__global__ __launch_bounds__(64) void fused_layer2(
    const ushort* __restrict__ xmq, const ushort* __restrict__ xsq,
    const int* __restrict__ offs_f, const int* __restrict__ csr_f,
    const int* __restrict__ offs_r, const int* __restrict__ csr_r,
    const ushort* __restrict__ Wls, const ushort* __restrict__ Wrs,
    const float* __restrict__ bls,
    const ushort* __restrict__ Wlm, const ushort* __restrict__ Wrm,
    const float* __restrict__ blm,
    ushort* __restrict__ nsq, ushort* __restrict__ nmq, int relu)
{
  __shared__ ushort mtile[16 * 128];  // 4 KB, 16B-slot XOR swizzle
  int side = blockIdx.x >= NBLK;
  int bidx = side ? blockIdx.x - NBLK : blockIdx.x;
  const ushort* xg   = side ? xsq    : xmq;
  const ushort* xs   = side ? xmq    : xsq;
  const int*    offs = side ? offs_r : offs_f;
  const int*    csr  = side ? csr_r  : csr_f;
  const ushort* Wl   = side ? Wlm    : Wls;
  const ushort* Wr   = side ? Wrm    : Wrs;
  const float*  bias = side ? blm    : bls;
  ushort*       Cout = side ? nmq    : nsq;

  int lane = threadIdx.x;
  int rowbase = bidx * 16;
  int t = lane >> 4, fr = lane & 15;
  const unsigned* X = (const unsigned*)xg;

  // prefetch self-side A fragments (independent of gather -> latency hidden)
  int srow = rowbase + fr;
  bf16x8 sfrag[4];
  #pragma unroll
  for (int ks = 0; ks < 4; ++ks)
    sfrag[ks] = *(const bf16x8*)(xs + (long)srow * H + (ks * 4 + t) * 8);

  // ---- phase 1: means (register gather, 8-deep) ----
  int wslot = lane >> 2;
  unsigned* mt32 = (unsigned*)mtile;
  for (int i = 0; i < 16; ++i) {
    int row = rowbase + i;
    int s = offs[row], e = offs[row + 1];
    float a0 = 0.f, a1 = 0.f;
    int j = s;
    for (; j + 8 <= e; j += 8) {
      long i0 = csr[j], i1 = csr[j+1], i2 = csr[j+2], i3 = csr[j+3];
      long i4 = csr[j+4], i5 = csr[j+5], i6 = csr[j+6], i7 = csr[j+7];
      unsigned x0 = X[i0*64+lane], x1 = X[i1*64+lane], x2 = X[i2*64+lane], x3 = X[i3*64+lane];
      unsigned x4 = X[i4*64+lane], x5 = X[i5*64+lane], x6 = X[i6*64+lane], x7 = X[i7*64+lane];
      a0 += b2f((ushort)(x0 & 0xffff)) + b2f((ushort)(x1 & 0xffff))
          + b2f((ushort)(x2 & 0xffff)) + b2f((ushort)(x3 & 0xffff))
          + b2f((ushort)(x4 & 0xffff)) + b2f((ushort)(x5 & 0xffff))
          + b2f((ushort)(x6 & 0xffff)) + b2f((ushort)(x7 & 0xffff));
      a1 += b2f((ushort)(x0 >> 16)) + b2f((ushort)(x1 >> 16))
          + b2f((ushort)(x2 >> 16)) + b2f((ushort)(x3 >> 16))
          + b2f((ushort)(x4 >> 16)) + b2f((ushort)(x5 >> 16))
          + b2f((ushort)(x6 >> 16)) + b2f((ushort)(x7 >> 16));
    }
    if (j + 4 <= e) {
      long i0 = csr[j], i1 = csr[j+1], i2 = csr[j+2], i3 = csr[j+3];
      unsigned x0 = X[i0*64+lane], x1 = X[i1*64+lane], x2 = X[i2*64+lane], x3 = X[i3*64+lane];
      a0 += b2f((ushort)(x0 & 0xffff)) + b2f((ushort)(x1 & 0xffff))
          + b2f((ushort)(x2 & 0xffff)) + b2f((ushort)(x3 & 0xffff));
      a1 += b2f((ushort)(x0 >> 16)) + b2f((ushort)(x1 >> 16))
          + b2f((ushort)(x2 >> 16)) + b2f((ushort)(x3 >> 16));
      j += 4;
    }
    for (; j < e; ++j) {
      unsigned x = X[(long)csr[j] * 64 + lane];
      a0 += b2f((ushort)(x & 0xffff));
      a1 += b2f((ushort)(x >> 16));
    }
    float inv = (e > s) ? 1.f / (float)(e - s) : 0.f;
    a0 *= inv; a1 *= inv;
    int sw = (wslot & 8) | ((wslot & 7) ^ (i & 7));
    mt32[i * 64 + sw * 4 + (lane & 3)] = (unsigned)f2b(a0) | ((unsigned)f2b(a1) << 16);
  }
  // wave-local LDS: no barrier needed (one wave per block)

  // ---- phase 2: GEMM ----
  f32x4 acc[8];
  #pragma unroll
  for (int c = 0; c < 8; ++c)
    #pragma unroll
    for (int q = 0; q < 4; ++q) acc[c][q] = 0.f;

  // mean side (A from LDS), K = 128
  #pragma unroll
  for (int ks = 0; ks < 4; ++ks) {
    int slot = ks * 4 + t;
    int sw = (slot & 8) | ((slot & 7) ^ (fr & 7));
    bf16x8 af = *(const bf16x8*)&mtile[fr * 128 + sw * 8];
    bf16x8 bfm[8];
    #pragma unroll
    for (int cc = 0; cc < 8; ++cc) {
      int col = cc * 16 + fr;
      bfm[cc] = *(const bf16x8*)(Wl + (long)col * H + slot * 8);
    }
    #pragma unroll
    for (int cc = 0; cc < 8; ++cc)
      acc[cc] = __builtin_amdgcn_mfma_f32_16x16x32_bf16(af, bfm[cc], acc[cc], 0, 0, 0);
  }
  // self side (A prefetched in registers), K = 128
  #pragma unroll
  for (int ks = 0; ks < 4; ++ks) {
    int slot = ks * 4 + t;
    bf16x8 bfm[8];
    #pragma unroll
    for (int cc = 0; cc < 8; ++cc) {
      int col = cc * 16 + fr;
      bfm[cc] = *(const bf16x8*)(Wr + (long)col * H + slot * 8);
    }
    #pragma unroll
    for (int cc = 0; cc < 8; ++cc)
      acc[cc] = __builtin_amdgcn_mfma_f32_16x16x32_bf16(sfrag[ks], bfm[cc], acc[cc], 0, 0, 0);
  }
  // epilogue
  #pragma unroll
  for (int cc = 0; cc < 8; ++cc)
    #pragma unroll
    for (int q = 0; q < 4; ++q) {
      int row = rowbase + t * 4 + q;
      int col = cc * 16 + fr;
      float v = acc[cc][q] + bias[col];
      if (relu) v = fmaxf(v, 0.f);
      Cout[(long)row * H + col] = f2b(v);
    }
}

// ---------------- degree count ----------------
__global__ void deg_count(const int* __restrict__ eidx, int* __restrict__ df, int* __restrict__ dr) {
  int e = blockIdx.x * blockDim.x + threadIdx.x;
  if (e >= NE) return;
  atomicAdd(dr + eidx[e], 1);
  atomicAdd(df + eidx[NE + e], 1);
}

// ---------------- dual exclusive scan: block 0 -> forward, block 1 -> reverse ----------------
__global__ __launch_bounds__(1024) void exscan2(
    const int* __restrict__ degf, const int* __restrict__ degr,
    int* __restrict__ offf, int* __restrict__ offr)
{
  __shared__ int part[1024];
  const int* deg = blockIdx.x ? degr : degf;
  int* offs = blockIdx.x ? offr : offf;
  int n = blockIdx.x ? NMQ : NSQ;
  int t = threadIdx.x;
  int chunk = (n + 1023) >> 10;
  int beg = t * chunk, end = beg + chunk;
  if (end > n) end = n;
  int s = 0;
  for (int i = beg; i < end; ++i) s += deg[i];
  part[t] = s;
  __syncthreads();
  for (int offd = 1; offd < 1024; offd <<= 1) {
    int v = 0;
    if (t >= offd) v = part[t - offd];
    __syncthreads();
    part[t] += v;
    __syncthreads();
  }
  int run = (t == 0) ? 0 : part[t - 1];
  for (int i = beg; i < end; ++i) { offs[i] = run; run += deg[i]; }
  if (t == 1023) offs[n] = part[1023];
}

// ---------------- CSR fill ----------------
__global__ void csr_fill(const int* __restrict__ eidx,
                         const int* __restrict__ offs_f, const int* __restrict__ offs_r,
                         int* __restrict__ cur_f, int* __restrict__ cur_r,
                         int* __restrict__ csr_f, int* __restrict__ csr_r) {
  int e = blockIdx.x * blockDim.x + threadIdx.x;
  if (e >= NE) return;
  int s = eidx[e], d = eidx[NE + e];
  int p = atomicAdd(cur_f + d, 1); csr_f[offs_f[d] + p] = s;
  int q = atomicAdd(cur_r + s, 1); csr_r[offs_r[s] + q] = d;
}

// ---------------- classifier: one wave per label edge ----------------
__global__ __launch_bounds__(256) void edge_dot_b(
    const ushort* __restrict__ xmq, const ushort* __restrict__ xsq,
    const int* __restrict__ eli, float* __restrict__ out)
{
  int wid = (blockIdx.x << 2) + (threadIdx.x >> 6);
  int lane = threadIdx.x & 63;
  if (wid >= NEL) return;
  int a = eli[wid], b = eli[NEL + wid];
  unsigned xa = ((const unsigned*)xmq)[(long)a * 64 + lane];
  unsigned xb = ((const unsigned*)xsq)[(long)b * 64 + lane];
  float p = b2f((ushort)(xa & 0xffff)) * b2f((ushort)(xb & 0xffff))
          + b2f((ushort)(xa >> 16))    * b2f((ushort)(xb >> 16));
  #pragma unroll
  for (int off = 32; off; off >>= 1) p += __shfl_down(p, off, 64);
  if (lane == 0) out[wid] = p;
}

extern "C" void kernel_launch(void* const* d_in, const int* in_sizes, int n_in,
                              void* d_out, int out_size, void* d_ws, size_t ws_size,
                              hipStream_t stream) {
  (void)in_sizes; (void)n_in; (void)out_size; (void)ws_size;
  // d_in[0]=mq_node_id (arange, unused), d_in[1]=sq_node_id (arange, unused)
  const float* sq_x      = (const float*)d_in[2];
  const int*   eidx      = (const int*)d_in[3];
  const int*   eli       = (const int*)d_in[4];
  const float* user_emb  = (const float*)d_in[5];
  const float* movie_emb = (const float*)d_in[6];
  const float* lin_W     = (const float*)d_in[7];
  const float* lin_b     = (const float*)d_in[8];
  const float* Wl_s      = (const float*)d_in[9];
  const float* bl_s      = (const float*)d_in[10];
  const float* Wr_s      = (const float*)d_in[11];
  const float* Wl_m      = (const float*)d_in[12];
  const float* bl_m      = (const float*)d_in[13];
  const float* Wr_m      = (const float*)d_in[14];
  float* out = (float*)d_out;

  char* ws = (char*)d_ws;
  size_t off = 0;
  auto alloc = [&](size_t bytes) {
    char* p = ws + off;
    off += (bytes + 255) & ~(size_t)255;
    return p;
  };
  ushort* xmq_a = (ushort*)alloc((size_t)NMQ * H * 2);
  ushort* xmq_b = (ushort*)alloc((size_t)NMQ * H * 2);
  ushort* xsq_a = (ushort*)alloc((size_t)NSQ * H * 2);
  ushort* xsq_b = (ushort*)alloc((size_t)NSQ * H * 2);
  ushort* linWb = (ushort*)alloc((size_t)H * FIN * 2);
  ushort* Wlsb  = (ushort*)alloc((size_t)NLAYERS * H * H * 2);
  ushort* Wrsb  = (ushort*)alloc((size_t)NLAYERS * H * H * 2);
  ushort* Wlmb  = (ushort*)alloc((size_t)NLAYERS * H * H * 2);
  ushort* Wrmb  = (ushort*)alloc((size_t)NLAYERS * H * H * 2);
  int* deg_f  = (int*)alloc((size_t)NSQ * 4);
  int* deg_r  = (int*)alloc((size_t)NMQ * 4);
  int* cur_f  = (int*)alloc((size_t)NSQ * 4);
  int* cur_r  = (int*)alloc((size_t)NMQ * 4);
  int* offs_f = (int*)alloc((size_t)(NSQ + 1) * 4);
  int* offs_r = (int*)alloc((size_t)(NMQ + 1) * 4);
  int* csr_f  = (int*)alloc((size_t)NE * 4);
  int* csr_r  = (int*)alloc((size_t)NE * 4);

  hipMemsetAsync(deg_f, 0, (char*)offs_f - (char*)deg_f, stream);

  // conversions (2 launches: embeddings + batched weights)
  cvt_bf16<<<(NMQ * H / 4 + 255) / 256, 256, 0, stream>>>(user_emb, xmq_a, NMQ * H / 4);
  cvt_w5<<<dim3((H * FIN / 4 + 255) / 256, 5), 256, 0, stream>>>(
      lin_W, Wl_s, Wr_s, Wl_m, Wr_m, linWb, Wlsb, Wrsb, Wlmb, Wrmb);

  encoder_mfma<<<NSQ / 16, 64, 0, stream>>>(sq_x, linWb, lin_b, movie_emb, xsq_a);
  deg_count<<<(NE + 255) / 256, 256, 0, stream>>>(eidx, deg_f, deg_r);
  exscan2<<<2, 1024, 0, stream>>>(deg_f, deg_r, offs_f, offs_r);
  csr_fill<<<(NE + 255) / 256, 256, 0, stream>>>(eidx, offs_f, offs_r, cur_f, cur_r, csr_f, csr_r);

  ushort *cm = xmq_a, *cs = xsq_a, *nm = xmq_b, *ns = xsq_b;
  for (int l = 0; l < NLAYERS; ++l) {
    fused_layer2<<<2 * NBLK, 64, 0, stream>>>(cm, cs, offs_f, csr_f, offs_r, csr_r,
        Wlsb + (size_t)l * H * H, Wrsb + (size_t)l * H * H, bl_s + (size_t)l * H,
        Wlmb + (size_t)l * H * H, Wrmb + (size_t)l * H * H, bl_m + (size_t)l * H,
        ns, nm, l == 0);
    ushort* t;
    t = cm; cm = nm; nm = t;
    t = cs; cs = ns; ns = t;
  }
  edge_dot_b<<<(NEL + 3) / 4, 256, 0, stream>>>(cm, cs, eli, out);
}

// Round 10
// 700.761 us; speedup vs baseline: 1.3302x; 1.0342x over previous
//
#include <hip/hip_runtime.h>

#define H    128
#define NMQ  50000
#define NSQ  50000
#define NE   600000
#define NEL  200000
#define FIN  768
#define NLAYERS 4
#define NBLK (NSQ / 16)   // blocks per side

typedef __attribute__((ext_vector_type(8))) short bf16x8;
typedef __attribute__((ext_vector_type(4))) float f32x4;

__device__ inline ushort f2b(float f) {
  unsigned u = __float_as_uint(f);
  u = (u + 0x7FFFu + ((u >> 16) & 1u)) >> 16;
  return (ushort)u;
}
__device__ inline float b2f(ushort h) { return __uint_as_float((unsigned)h << 16); }

// ---------------- fp32 -> bf16 convert (n divisible by 4) ----------------
__global__ void cvt_bf16(const float* __restrict__ in, ushort* __restrict__ out, int n4) {
  int i = blockIdx.x * blockDim.x + threadIdx.x;
  if (i >= n4) return;
  float4 v = ((const float4*)in)[i];
  ushort4 o;
  o.x = f2b(v.x); o.y = f2b(v.y); o.z = f2b(v.z); o.w = f2b(v.w);
  ((ushort4*)out)[i] = o;
}

// ---------------- batched weight convert: 5 tensors via blockIdx.y ----------------
__global__ void cvt_w5(const float* __restrict__ linW,
                       const float* __restrict__ Wls, const float* __restrict__ Wrs,
                       const float* __restrict__ Wlm, const float* __restrict__ Wrm,
                       ushort* olinW, ushort* oWls, ushort* oWrs, ushort* oWlm, ushort* oWrm) {
  const float* in; ushort* out; int n4;
  switch (blockIdx.y) {
    case 0: in = linW; out = olinW; n4 = H * FIN / 4; break;
    case 1: in = Wls;  out = oWls;  n4 = NLAYERS * H * H / 4; break;
    case 2: in = Wrs;  out = oWrs;  n4 = NLAYERS * H * H / 4; break;
    case 3: in = Wlm;  out = oWlm;  n4 = NLAYERS * H * H / 4; break;
    default: in = Wrm; out = oWrm;  n4 = NLAYERS * H * H / 4; break;
  }
  int i = blockIdx.x * blockDim.x + threadIdx.x;
  if (i >= n4) return;
  float4 v = ((const float4*)in)[i];
  ushort4 o;
  o.x = f2b(v.x); o.y = f2b(v.y); o.z = f2b(v.z); o.w = f2b(v.w);
  ((ushort4*)out)[i] = o;
}

// ---------------- encoder: x_sq = bf16(sq_x @ lin_W^T + lin_b + movie_emb) ----------------
// One wave per 16 rows. Unroll-by-2 with explicit A-prefetch ping-pong:
// next iteration's HBM loads stay in flight under current W-loads + MFMAs.
__global__ __launch_bounds__(64) void encoder_mfma(
    const float* __restrict__ A, const ushort* __restrict__ Wb,
    const float* __restrict__ bias, const float* __restrict__ memb,
    ushort* __restrict__ C)
{
  int lane = threadIdx.x;
  int rowbase = blockIdx.x * 16;
  int t = lane >> 4, fr = lane & 15;
  f32x4 acc[8];
  #pragma unroll
  for (int c = 0; c < 8; ++c)
    #pragma unroll
    for (int q = 0; q < 4; ++q) acc[c][q] = 0.f;

  int arow = rowbase + fr;           // 50000 % 16 == 0
  const float* Ab = A + (long)arow * FIN + t * 8;

#define ENC_COMPUTE(k0, c0, c1) do {                                        \
    ushort tmp[8];                                                          \
    tmp[0] = f2b((c0).x); tmp[1] = f2b((c0).y);                             \
    tmp[2] = f2b((c0).z); tmp[3] = f2b((c0).w);                             \
    tmp[4] = f2b((c1).x); tmp[5] = f2b((c1).y);                             \
    tmp[6] = f2b((c1).z); tmp[7] = f2b((c1).w);                             \
    bf16x8 af = *(bf16x8*)tmp;                                              \
    bf16x8 bfm[8];                                                          \
    _Pragma("unroll")                                                       \
    for (int cc = 0; cc < 8; ++cc) {                                        \
      int col = cc * 16 + fr;                                               \
      bfm[cc] = *(const bf16x8*)(Wb + (long)col * FIN + (k0) + t * 8);      \
    }                                                                       \
    _Pragma("unroll")                                                       \
    for (int cc = 0; cc < 8; ++cc)                                          \
      acc[cc] = __builtin_amdgcn_mfma_f32_16x16x32_bf16(af, bfm[cc], acc[cc], 0, 0, 0); \
  } while (0)

  float4 u0 = *(const float4*)Ab;
  float4 u1 = *(const float4*)(Ab + 4);
  for (int ki = 0; ki < FIN / 32; ki += 2) {
    float4 v0 = *(const float4*)(Ab + (ki + 1) * 32);
    float4 v1 = *(const float4*)(Ab + (ki + 1) * 32 + 4);
    ENC_COMPUTE(ki * 32, u0, u1);
    if (ki + 2 < FIN / 32) {
      u0 = *(const float4*)(Ab + (ki + 2) * 32);
      u1 = *(const float4*)(Ab + (ki + 2) * 32 + 4);
    }
    ENC_COMPUTE((ki + 1) * 32, v0, v1);
  }
#undef ENC_COMPUTE

  #pragma unroll
  for (int cc = 0; cc < 8; ++cc)
    #pragma unroll
    for (int q = 0; q < 4; ++q) {
      int row = rowbase + t * 4 + q;
      int col = cc * 16 + fr;
      float v = acc[cc][q] + bias[col] + memb[(long)row * H + col];
      C[(long)row * H + col] = f2b(v);
    }
}

// ---------------- merged both-sides fused SpMM-mean + SAGE GEMM ----------------
// Gather phase: flat edge-walk over the block's CSR range, 16-deep ping-pong
// register staging (up to 32 row-loads in flight/wave), run-length flush by drow.
__global__ __launch_bounds__(64) void fused_layer2(
    const ushort* __restrict__ xmq, const ushort* __restrict__ xsq,
    const int* __restrict__ offs_f, const int* __restrict__ csr_f,
    const int* __restrict__ drow_f,
    const int* __restrict__ offs_r, const int* __restrict__ csr_r,
    const int* __restrict__ drow_r,
    const ushort* __restrict__ Wls, const ushort* __restrict__ Wrs,
    const float* __restrict__ bls,
    const ushort* __restrict__ Wlm, const ushort* __restrict__ Wrm,
    const float* __restrict__ blm,
    ushort* __restrict__ nsq, ushort* __restrict__ nmq, int relu)
{
  __shared__ ushort mtile[16 * 128];  // 4 KB, 16B-slot XOR swizzle
  int side = blockIdx.x >= NBLK;
  int bidx = side ? blockIdx.x - NBLK : blockIdx.x;
  const ushort* xg   = side ? xsq    : xmq;
  const ushort* xs   = side ? xmq    : xsq;
  const int*    offs = side ? offs_r : offs_f;
  const int*    csr  = side ? csr_r  : csr_f;
  const int*    drow = side ? drow_r : drow_f;
  const ushort* Wl   = side ? Wlm    : Wls;
  const ushort* Wr   = side ? Wrm    : Wrs;
  const float*  bias = side ? blm    : bls;
  ushort*       Cout = side ? nmq    : nsq;

  int lane = threadIdx.x;
  int rowbase = bidx * 16;
  int t = lane >> 4, fr = lane & 15;
  const unsigned* X = (const unsigned*)xg;

  // prefetch self-side A fragments (independent of gather)
  int srow = rowbase + fr;
  bf16x8 sfrag[4];
  #pragma unroll
  for (int ks = 0; ks < 4; ++ks)
    sfrag[ks] = *(const bf16x8*)(xs + (long)srow * H + (ks * 4 + t) * 8);

  // ---- phase 1: means (flat edge walk, double-buffered 16-deep) ----
  int wslot = lane >> 2;
  unsigned* mt32 = (unsigned*)mtile;
  #pragma unroll
  for (int i = 0; i < 16; ++i) mt32[i * 64 + lane] = 0;

  int cbeg = offs[rowbase], cend = offs[rowbase + 16];
  float a0 = 0.f, a1 = 0.f;
  int cur = -1, cnt = 0;

#define GISSUE(ax, rx, c0, nn) do {                                         \
    if ((nn) == 16) {                                                       \
      _Pragma("unroll")                                                     \
      for (int j = 0; j < 16; ++j) {                                        \
        rx[j] = drow[(c0) + j];                                             \
        ax[j] = X[(long)csr[(c0) + j] * 64 + lane];                         \
      }                                                                     \
    } else {                                                                \
      _Pragma("unroll")                                                     \
      for (int j = 0; j < 16; ++j) if (j < (nn)) {                          \
        rx[j] = drow[(c0) + j];                                             \
        ax[j] = X[(long)csr[(c0) + j] * 64 + lane];                         \
      }                                                                     \
    } } while (0)

#define GCONSUME(ax, rx, nn) do {                                           \
    _Pragma("unroll")                                                       \
    for (int j = 0; j < 16; ++j) if (j < (nn)) {                            \
      int rowj = rx[j];                                                     \
      if (rowj != cur) {                                                    \
        if (cnt > 0) {                                                      \
          float inv = 1.f / (float)cnt;                                     \
          int sw = (wslot & 8) | ((wslot & 7) ^ (cur & 7));                 \
          mt32[(cur & 15) * 64 + sw * 4 + (lane & 3)] =                     \
              (unsigned)f2b(a0 * inv) | ((unsigned)f2b(a1 * inv) << 16);    \
        }                                                                   \
        cur = rowj; a0 = 0.f; a1 = 0.f; cnt = 0;                            \
      }                                                                     \
      unsigned w = ax[j];                                                   \
      a0 += b2f((ushort)(w & 0xffff));                                      \
      a1 += b2f((ushort)(w >> 16));                                         \
      ++cnt;                                                                \
    } } while (0)

  {
    unsigned aA[16], aB[16];
    int rA[16], rB[16];
    int c = cbeg;
    int nA = cend - c; if (nA > 16) nA = 16;
    if (nA > 0) GISSUE(aA, rA, c, nA);
    c += nA;
    while (nA > 0) {
      int nB = cend - c; if (nB > 16) nB = 16;
      if (nB > 0) GISSUE(aB, rB, c, nB);
      c += nB;
      GCONSUME(aA, rA, nA);
      if (nB == 0) break;
      nA = cend - c; if (nA > 16) nA = 16;
      if (nA > 0) GISSUE(aA, rA, c, nA);
      c += nA;
      GCONSUME(aB, rB, nB);
    }
    if (cnt > 0) {
      float inv = 1.f / (float)cnt;
      int sw = (wslot & 8) | ((wslot & 7) ^ (cur & 7));
      mt32[(cur & 15) * 64 + sw * 4 + (lane & 3)] =
          (unsigned)f2b(a0 * inv) | ((unsigned)f2b(a1 * inv) << 16);
    }
  }
#undef GISSUE
#undef GCONSUME
  // wave-local LDS: no barrier needed (one wave per block)

  // ---- phase 2: GEMM ----
  f32x4 acc[8];
  #pragma unroll
  for (int c = 0; c < 8; ++c)
    #pragma unroll
    for (int q = 0; q < 4; ++q) acc[c][q] = 0.f;

  // mean side (A from LDS), K = 128
  #pragma unroll
  for (int ks = 0; ks < 4; ++ks) {
    int slot = ks * 4 + t;
    int sw = (slot & 8) | ((slot & 7) ^ (fr & 7));
    bf16x8 af = *(const bf16x8*)&mtile[fr * 128 + sw * 8];
    bf16x8 bfm[8];
    #pragma unroll
    for (int cc = 0; cc < 8; ++cc) {
      int col = cc * 16 + fr;
      bfm[cc] = *(const bf16x8*)(Wl + (long)col * H + slot * 8);
    }
    #pragma unroll
    for (int cc = 0; cc < 8; ++cc)
      acc[cc] = __builtin_amdgcn_mfma_f32_16x16x32_bf16(af, bfm[cc], acc[cc], 0, 0, 0);
  }
  // self side (A prefetched in registers), K = 128
  #pragma unroll
  for (int ks = 0; ks < 4; ++ks) {
    int slot = ks * 4 + t;
    bf16x8 bfm[8];
    #pragma unroll
    for (int cc = 0; cc < 8; ++cc) {
      int col = cc * 16 + fr;
      bfm[cc] = *(const bf16x8*)(Wr + (long)col * H + slot * 8);
    }
    #pragma unroll
    for (int cc = 0; cc < 8; ++cc)
      acc[cc] = __builtin_amdgcn_mfma_f32_16x16x32_bf16(sfrag[ks], bfm[cc], acc[cc], 0, 0, 0);
  }
  // epilogue
  #pragma unroll
  for (int cc = 0; cc < 8; ++cc)
    #pragma unroll
    for (int q = 0; q < 4; ++q) {
      int row = rowbase + t * 4 + q;
      int col = cc * 16 + fr;
      float v = acc[cc][q] + bias[col];
      if (relu) v = fmaxf(v, 0.f);
      Cout[(long)row * H + col] = f2b(v);
    }
}

// ---------------- degree count ----------------
__global__ void deg_count(const int* __restrict__ eidx, int* __restrict__ df, int* __restrict__ dr) {
  int e = blockIdx.x * blockDim.x + threadIdx.x;
  if (e >= NE) return;
  atomicAdd(dr + eidx[e], 1);
  atomicAdd(df + eidx[NE + e], 1);
}

// ---------------- dual exclusive scan: block 0 -> forward, block 1 -> reverse ----------------
__global__ __launch_bounds__(1024) void exscan2(
    const int* __restrict__ degf, const int* __restrict__ degr,
    int* __restrict__ offf, int* __restrict__ offr)
{
  __shared__ int part[1024];
  const int* deg = blockIdx.x ? degr : degf;
  int* offs = blockIdx.x ? offr : offf;
  int n = blockIdx.x ? NMQ : NSQ;
  int t = threadIdx.x;
  int chunk = (n + 1023) >> 10;
  int beg = t * chunk, end = beg + chunk;
  if (end > n) end = n;
  int s = 0;
  for (int i = beg; i < end; ++i) s += deg[i];
  part[t] = s;
  __syncthreads();
  for (int offd = 1; offd < 1024; offd <<= 1) {
    int v = 0;
    if (t >= offd) v = part[t - offd];
    __syncthreads();
    part[t] += v;
    __syncthreads();
  }
  int run = (t == 0) ? 0 : part[t - 1];
  for (int i = beg; i < end; ++i) { offs[i] = run; run += deg[i]; }
  if (t == 1023) offs[n] = part[1023];
}

// ---------------- CSR fill (records dst row per slot) ----------------
__global__ void csr_fill(const int* __restrict__ eidx,
                         const int* __restrict__ offs_f, const int* __restrict__ offs_r,
                         int* __restrict__ cur_f, int* __restrict__ cur_r,
                         int* __restrict__ csr_f, int* __restrict__ csr_r,
                         int* __restrict__ drow_f, int* __restrict__ drow_r) {
  int e = blockIdx.x * blockDim.x + threadIdx.x;
  if (e >= NE) return;
  int s = eidx[e], d = eidx[NE + e];
  int p = atomicAdd(cur_f + d, 1); int pf = offs_f[d] + p; csr_f[pf] = s; drow_f[pf] = d;
  int q = atomicAdd(cur_r + s, 1); int pr = offs_r[s] + q; csr_r[pr] = d; drow_r[pr] = s;
}

// ---------------- classifier: one wave per label edge ----------------
__global__ __launch_bounds__(256) void edge_dot_b(
    const ushort* __restrict__ xmq, const ushort* __restrict__ xsq,
    const int* __restrict__ eli, float* __restrict__ out)
{
  int wid = (blockIdx.x << 2) + (threadIdx.x >> 6);
  int lane = threadIdx.x & 63;
  if (wid >= NEL) return;
  int a = eli[wid], b = eli[NEL + wid];
  unsigned xa = ((const unsigned*)xmq)[(long)a * 64 + lane];
  unsigned xb = ((const unsigned*)xsq)[(long)b * 64 + lane];
  float p = b2f((ushort)(xa & 0xffff)) * b2f((ushort)(xb & 0xffff))
          + b2f((ushort)(xa >> 16))    * b2f((ushort)(xb >> 16));
  #pragma unroll
  for (int off = 32; off; off >>= 1) p += __shfl_down(p, off, 64);
  if (lane == 0) out[wid] = p;
}

extern "C" void kernel_launch(void* const* d_in, const int* in_sizes, int n_in,
                              void* d_out, int out_size, void* d_ws, size_t ws_size,
                              hipStream_t stream) {
  (void)in_sizes; (void)n_in; (void)out_size; (void)ws_size;
  // d_in[0]=mq_node_id (arange, unused), d_in[1]=sq_node_id (arange, unused)
  const float* sq_x      = (const float*)d_in[2];
  const int*   eidx      = (const int*)d_in[3];
  const int*   eli       = (const int*)d_in[4];
  const float* user_emb  = (const float*)d_in[5];
  const float* movie_emb = (const float*)d_in[6];
  const float* lin_W     = (const float*)d_in[7];
  const float* lin_b     = (const float*)d_in[8];
  const float* Wl_s      = (const float*)d_in[9];
  const float* bl_s      = (const float*)d_in[10];
  const float* Wr_s      = (const float*)d_in[11];
  const float* Wl_m      = (const float*)d_in[12];
  const float* bl_m      = (const float*)d_in[13];
  const float* Wr_m      = (const float*)d_in[14];
  float* out = (float*)d_out;

  char* ws = (char*)d_ws;
  size_t off = 0;
  auto alloc = [&](size_t bytes) {
    char* p = ws + off;
    off += (bytes + 255) & ~(size_t)255;
    return p;
  };
  ushort* xmq_a = (ushort*)alloc((size_t)NMQ * H * 2);
  ushort* xmq_b = (ushort*)alloc((size_t)NMQ * H * 2);
  ushort* xsq_a = (ushort*)alloc((size_t)NSQ * H * 2);
  ushort* xsq_b = (ushort*)alloc((size_t)NSQ * H * 2);
  ushort* linWb = (ushort*)alloc((size_t)H * FIN * 2);
  ushort* Wlsb  = (ushort*)alloc((size_t)NLAYERS * H * H * 2);
  ushort* Wrsb  = (ushort*)alloc((size_t)NLAYERS * H * H * 2);
  ushort* Wlmb  = (ushort*)alloc((size_t)NLAYERS * H * H * 2);
  ushort* Wrmb  = (ushort*)alloc((size_t)NLAYERS * H * H * 2);
  int* deg_f  = (int*)alloc((size_t)NSQ * 4);
  int* deg_r  = (int*)alloc((size_t)NMQ * 4);
  int* cur_f  = (int*)alloc((size_t)NSQ * 4);
  int* cur_r  = (int*)alloc((size_t)NMQ * 4);
  int* offs_f = (int*)alloc((size_t)(NSQ + 1) * 4);
  int* offs_r = (int*)alloc((size_t)(NMQ + 1) * 4);
  int* csr_f  = (int*)alloc((size_t)NE * 4);
  int* csr_r  = (int*)alloc((size_t)NE * 4);
  int* drow_f = (int*)alloc((size_t)NE * 4);
  int* drow_r = (int*)alloc((size_t)NE * 4);

  hipMemsetAsync(deg_f, 0, (char*)offs_f - (char*)deg_f, stream);

  // conversions (2 launches: embeddings + batched weights)
  cvt_bf16<<<(NMQ * H / 4 + 255) / 256, 256, 0, stream>>>(user_emb, xmq_a, NMQ * H / 4);
  cvt_w5<<<dim3((H * FIN / 4 + 255) / 256, 5), 256, 0, stream>>>(
      lin_W, Wl_s, Wr_s, Wl_m, Wr_m, linWb, Wlsb, Wrsb, Wlmb, Wrmb);

  encoder_mfma<<<NSQ / 16, 64, 0, stream>>>(sq_x, linWb, lin_b, movie_emb, xsq_a);
  deg_count<<<(NE + 255) / 256, 256, 0, stream>>>(eidx, deg_f, deg_r);
  exscan2<<<2, 1024, 0, stream>>>(deg_f, deg_r, offs_f, offs_r);
  csr_fill<<<(NE + 255) / 256, 256, 0, stream>>>(eidx, offs_f, offs_r, cur_f, cur_r,
                                                 csr_f, csr_r, drow_f, drow_r);

  ushort *cm = xmq_a, *cs = xsq_a, *nm = xmq_b, *ns = xsq_b;
  for (int l = 0; l < NLAYERS; ++l) {
    fused_layer2<<<2 * NBLK, 64, 0, stream>>>(cm, cs,
        offs_f, csr_f, drow_f, offs_r, csr_r, drow_r,
        Wlsb + (size_t)l * H * H, Wrsb + (size_t)l * H * H, bl_s + (size_t)l * H,
        Wlmb + (size_t)l * H * H, Wrmb + (size_t)l * H * H, bl_m + (size_t)l * H,
        ns, nm, l == 0);
    ushort* t;
    t = cm; cm = nm; nm = t;
    t = cs; cs = ns; ns = t;
  }
  edge_dot_b<<<(NEL + 3) / 4, 256, 0, stream>>>(cm, cs, eli, out);
}